// Round 6
// baseline (483.174 us; speedup 1.0000x reference)
//
#include <hip/hip_runtime.h>
#include <stdint.h>

typedef __attribute__((ext_vector_type(8))) short short8;   // 8 x bf16 MFMA operand
typedef __attribute__((ext_vector_type(4))) float floatx4;  // MFMA accumulator

#define DEV __device__ __forceinline__

DEV unsigned short f2bf(float x) {  // fp32 -> bf16 RNE
  unsigned u = __float_as_uint(x);
  u += 0x7fffu + ((u >> 16) & 1u);
  return (unsigned short)(u >> 16);
}

DEV void load_lds16(const unsigned short* g, unsigned short* l) {
  __builtin_amdgcn_global_load_lds(
      (const __attribute__((address_space(1))) void*)g,
      (__attribute__((address_space(3))) void*)l, 16, 0, 0);
}

// ---------------- weight fp32 -> bf16 ----------------
__global__ void cvt_kernel(const float* __restrict__ in, unsigned short* __restrict__ out) {
  int i = (blockIdx.x * 256 + threadIdx.x) * 4;
  float4 v = *(const float4*)(in + i);
  ushort4 o;
  o.x = f2bf(v.x); o.y = f2bf(v.y); o.z = f2bf(v.z); o.w = f2bf(v.w);
  *(ushort4*)(out + i) = o;
}

// ---------------- 128x128 tile bf16 GEMM: Y = A @ W^T (+bias) ----------------
// MODE 1: A fp32 [8192,1024] (converted during staging), out bf16 head-split [B,H,S,64]
// MODE 0: A bf16 [8192,1024] (async staging),            out fp32 flat [8192,1024]
template<int MODE>
__global__ __launch_bounds__(256, 2) void gemm128(
    const void* __restrict__ Ap, const unsigned short* __restrict__ Bw,
    const float* __restrict__ bias, void* __restrict__ Outp) {
  __shared__ alignas(16) unsigned short As[128 * 32];  // 8192 B each
  __shared__ alignas(16) unsigned short Bs[128 * 32];
  const int tid = threadIdx.x;
  const int lane = tid & 63;
  const int wave = tid >> 6;
  const int lcol = lane & 15;
  const int quad = lane >> 4;
  const int n0 = blockIdx.x * 128;
  const int m0 = blockIdx.y * 128;
  const int wm = (wave & 1) * 64;
  const int wn = (wave >> 1) * 64;

  floatx4 acc[4][4];
  for (int mi = 0; mi < 4; ++mi)
    for (int ni = 0; ni < 4; ++ni)
      for (int r = 0; r < 4; ++r) acc[mi][ni][r] = 0.f;

  for (int kt = 0; kt < 32; ++kt) {
    const int k0 = kt * 32;
    {  // B tile (8192 B): 2 x 256 threads x 16 B = exact cover
      int c = tid;
      load_lds16(Bw + (size_t)(n0 + (c >> 2)) * 1024 + k0 + (c & 3) * 8, Bs + c * 8);
      c = tid + 256;
      load_lds16(Bw + (size_t)(n0 + (c >> 2)) * 1024 + k0 + (c & 3) * 8, Bs + c * 8);
    }
    if (MODE == 1) {  // A tile: fp32 load + in-register convert
      const float* A = (const float*)Ap;
#pragma unroll
      for (int i = 0; i < 4; ++i) {
        int f = tid + i * 256;
        int row = f >> 3, c4 = f & 7;
        float4 v = *(const float4*)(A + (size_t)(m0 + row) * 1024 + k0 + c4 * 4);
        ushort4 o; o.x = f2bf(v.x); o.y = f2bf(v.y); o.z = f2bf(v.z); o.w = f2bf(v.w);
        *(ushort4*)(As + row * 32 + c4 * 4) = o;
      }
    } else {  // A tile: bf16 async (exact 8192-B cover)
      const unsigned short* A = (const unsigned short*)Ap;
      int c = tid;
      load_lds16(A + (size_t)(m0 + (c >> 2)) * 1024 + k0 + (c & 3) * 8, As + c * 8);
      c = tid + 256;
      load_lds16(A + (size_t)(m0 + (c >> 2)) * 1024 + k0 + (c & 3) * 8, As + c * 8);
    }
    __syncthreads();
    short8 af[4], bf[4];
#pragma unroll
    for (int mi = 0; mi < 4; ++mi)
      af[mi] = *(const short8*)(As + (wm + mi * 16 + lcol) * 32 + quad * 8);  // 64B-stride rows: aligned
#pragma unroll
    for (int ni = 0; ni < 4; ++ni)
      bf[ni] = *(const short8*)(Bs + (wn + ni * 16 + lcol) * 32 + quad * 8);
#pragma unroll
    for (int mi = 0; mi < 4; ++mi)
#pragma unroll
      for (int ni = 0; ni < 4; ++ni)
        acc[mi][ni] = __builtin_amdgcn_mfma_f32_16x16x32_bf16(af[mi], bf[ni], acc[mi][ni], 0, 0, 0);
    __syncthreads();
  }

  if (MODE == 1) {
    unsigned short* Out = (unsigned short*)Outp;
#pragma unroll
    for (int ni = 0; ni < 4; ++ni) {
      int col = n0 + wn + ni * 16 + lcol;
      float bv = bias[col];
      int h = col >> 6, d = col & 63;
#pragma unroll
      for (int mi = 0; mi < 4; ++mi) {
        int rbase = m0 + wm + mi * 16 + quad * 4;
#pragma unroll
        for (int r = 0; r < 4; ++r) {
          int grow = rbase + r;            // = b*2048 + s
          int bb = grow >> 11, s = grow & 2047;
          Out[((size_t)(bb * 16 + h) * 2048 + s) * 64 + d] = f2bf(acc[mi][ni][r] + bv);
        }
      }
    }
  } else {
    float* Out = (float*)Outp;
#pragma unroll
    for (int ni = 0; ni < 4; ++ni) {
      int col = n0 + wn + ni * 16 + lcol;
      float bv = bias[col];
#pragma unroll
      for (int mi = 0; mi < 4; ++mi) {
        int rbase = m0 + wm + mi * 16 + quad * 4;
#pragma unroll
        for (int r = 0; r < 4; ++r)
          Out[(size_t)(rbase + r) * 1024 + col] = acc[mi][ni][r] + bv;
      }
    }
  }
}

// ---------------- flash attention: one block = (b, h, 128 q rows) ----------------
// Round-5 fix kept: 16384-B tiles need FOUR load_lds16 calls/thread.
// Round-6 fix: Pch row stride 72 -> 88 shorts (176 B, multiple of 16). Stride 72
// (144 B) made every odd-q ds_read_b128 of P fragments / epilogue uint4 reads
// misaligned (addr % 16 == 8) -> align-down into the PREVIOUS row's uninit
// 16-B pad -> bf16 NaN encodings -> PV MFMA NaN. This generator existed in all
// five failed rounds and masked every dtype experiment.
#define PSTR 88
__global__ __launch_bounds__(256, 2) void attn_kernel(
    const unsigned short* __restrict__ Qp, const unsigned short* __restrict__ Kp,
    const unsigned short* __restrict__ Vp, unsigned short* __restrict__ Ctx) {
  __shared__ alignas(16) unsigned short Ks[128 * 64];     // 16384 B (Q staging, then K tiles)
  __shared__ alignas(16) unsigned int Vt2[64 * 68];       // 17408 B (272-B rows: 16-aligned)
  __shared__ alignas(16) unsigned short Pch[128 * PSTR];  // 22528 B: P chunks / V staging / O staging
  __shared__ float alphaS[128];
  __shared__ float linvS[128];

  const int tid = threadIdx.x;
  const int lane = tid & 63, wave = tid >> 6;
  const int lcol = lane & 15, quad = lane >> 4;
  const int wq = wave * 32;  // this wave's 32 q rows
  const int qt = blockIdx.x, h = blockIdx.y, b = blockIdx.z;
  const size_t bh = (size_t)(b * 16 + h) * 2048 * 64;
  const unsigned short* Qb = Qp + bh + (size_t)qt * 128 * 64;
  const unsigned short* Kb = Kp + bh;
  const unsigned short* Vb = Vp + bh;
  unsigned short* Vs = Pch;  // [128][64] overlay, dead after transpose

  // prologue: stage full 16384-B Q tile (4 calls), keep fragments in registers
#pragma unroll
  for (int i = 0; i < 4; ++i)
    load_lds16(Qb + (tid + i * 256) * 8, Ks + (tid + i * 256) * 8);
  __syncthreads();
  short8 qf[2][2];
#pragma unroll
  for (int ni = 0; ni < 2; ++ni)
#pragma unroll
    for (int ks = 0; ks < 2; ++ks)
      qf[ni][ks] = *(const short8*)(Ks + (wq + ni * 16 + lcol) * 64 + ks * 32 + quad * 8);

  float M[2] = {-1e30f, -1e30f};
  float L[2] = {0.f, 0.f};
  floatx4 Oacc[2][4];
  for (int mi = 0; mi < 2; ++mi)
    for (int nd = 0; nd < 4; ++nd)
      for (int r = 0; r < 4; ++r) Oacc[mi][nd][r] = 0.f;

  const float sc = 0.125f * 1.44269504089f;  // 1/sqrt(64) * log2(e)

  for (int jt = 0; jt < 16; ++jt) {
    __syncthreads();  // B0: all waves done reading Ks/Vt2/Pch before restage
#pragma unroll
    for (int i = 0; i < 4; ++i) {
      load_lds16(Kb + (size_t)jt * 8192 + (tid + i * 256) * 8, Ks + (tid + i * 256) * 8);
      load_lds16(Vb + (size_t)jt * 8192 + (tid + i * 256) * 8, Vs + (tid + i * 256) * 8);
    }
    __syncthreads();  // B1: tiles visible

    {  // transpose V -> Vt2 (packed s-pairs)
      int d = tid & 63;
      int sp0 = (tid >> 6) * 16;
#pragma unroll
      for (int i = 0; i < 16; ++i) {
        int sp = sp0 + i;
        unsigned lo = Vs[(2 * sp) * 64 + d];
        unsigned hi = Vs[(2 * sp + 1) * 64 + d];
        Vt2[d * 68 + sp] = lo | (hi << 16);
      }
    }

    // S^T = K @ Q^T : m = kcol (8 tiles), n = q (2 tiles)
    floatx4 sacc[8][2];
    for (int mi = 0; mi < 8; ++mi)
      for (int ni = 0; ni < 2; ++ni)
        for (int r = 0; r < 4; ++r) sacc[mi][ni][r] = 0.f;
#pragma unroll
    for (int mi = 0; mi < 8; ++mi) {
      short8 kf0 = *(const short8*)(Ks + (mi * 16 + lcol) * 64 + quad * 8);
      short8 kf1 = *(const short8*)(Ks + (mi * 16 + lcol) * 64 + 32 + quad * 8);
#pragma unroll
      for (int ni = 0; ni < 2; ++ni) {
        sacc[mi][ni] = __builtin_amdgcn_mfma_f32_16x16x32_bf16(kf0, qf[ni][0], sacc[mi][ni], 0, 0, 0);
        sacc[mi][ni] = __builtin_amdgcn_mfma_f32_16x16x32_bf16(kf1, qf[ni][1], sacc[mi][ni], 0, 0, 0);
      }
    }
    __syncthreads();  // B2: Vt2 ready everywhere; Vs fully read -> Pch reusable

    // online softmax over kcol (per lane: fixed q = wq + ni*16 + lcol)
    float alpha[2];
#pragma unroll
    for (int ni = 0; ni < 2; ++ni) {
      float mx = -1e30f;
#pragma unroll
      for (int mi = 0; mi < 8; ++mi)
#pragma unroll
        for (int r = 0; r < 4; ++r) mx = fmaxf(mx, sacc[mi][ni][r]);
      mx = fmaxf(mx, __shfl_xor(mx, 16));
      mx = fmaxf(mx, __shfl_xor(mx, 32));
      float mnew = fmaxf(M[ni], mx * sc);
      alpha[ni] = exp2f(M[ni] - mnew);
      M[ni] = mnew;
      float rs = 0.f;
#pragma unroll
      for (int mi = 0; mi < 8; ++mi)
#pragma unroll
        for (int r = 0; r < 4; ++r) {
          float p = exp2f(sacc[mi][ni][r] * sc - mnew);
          sacc[mi][ni][r] = p;
          rs += p;
        }
      rs += __shfl_xor(rs, 16);
      rs += __shfl_xor(rs, 32);
      L[ni] = L[ni] * alpha[ni] + rs;
      if (quad == 0) alphaS[wq + ni * 16 + lcol] = alpha[ni];
    }
    // rescale O (O rows indexed by C-layout; alpha via LDS, wave-private rows)
#pragma unroll
    for (int mi = 0; mi < 2; ++mi)
#pragma unroll
      for (int r = 0; r < 4; ++r) {
        float a = alphaS[wq + mi * 16 + quad * 4 + r];
#pragma unroll
        for (int nd = 0; nd < 4; ++nd) Oacc[mi][nd][r] *= a;
      }

    // P -> LDS (packed b64 writes) + PV, two kcol halves, barrier-fenced.
#pragma unroll
    for (int half = 0; half < 2; ++half) {
#pragma unroll
      for (int ni = 0; ni < 2; ++ni) {
        int q = wq + ni * 16 + lcol;
#pragma unroll
        for (int m2 = 0; m2 < 4; ++m2) {
          int mi = half * 4 + m2;
          ushort4 pk;
          pk.x = f2bf(sacc[mi][ni][0]);
          pk.y = f2bf(sacc[mi][ni][1]);
          pk.z = f2bf(sacc[mi][ni][2]);
          pk.w = f2bf(sacc[mi][ni][3]);
          *(ushort4*)(Pch + q * PSTR + m2 * 16 + quad * 4) = pk;
        }
      }
      __syncthreads();  // B3: P stores visible before fragment reads
#pragma unroll
      for (int kk = 0; kk < 2; ++kk) {
        short8 pf[2];
#pragma unroll
        for (int mi = 0; mi < 2; ++mi)
          pf[mi] = *(const short8*)(Pch + (wq + mi * 16 + lcol) * PSTR + kk * 32 + quad * 8);
#pragma unroll
        for (int nd = 0; nd < 4; ++nd) {
          short8 vf = *(const short8*)(&Vt2[(nd * 16 + lcol) * 68 + (half * 2 + kk) * 16 + quad * 4]);
#pragma unroll
          for (int mi = 0; mi < 2; ++mi)
            Oacc[mi][nd] = __builtin_amdgcn_mfma_f32_16x16x32_bf16(pf[mi], vf, Oacc[mi][nd], 0, 0, 0);
        }
      }
      __syncthreads();  // B4: P reads done before next half / next iter overwrites
    }
  }

  // epilogue: O / L -> bf16, stage in Pch (wave-private rows), coalesced store
#pragma unroll
  for (int ni = 0; ni < 2; ++ni)
    if (quad == 0) linvS[wq + ni * 16 + lcol] = 1.f / L[ni];
#pragma unroll
  for (int mi = 0; mi < 2; ++mi)
#pragma unroll
    for (int r = 0; r < 4; ++r) {
      int q = wq + mi * 16 + quad * 4 + r;
      float li = linvS[q];
#pragma unroll
      for (int nd = 0; nd < 4; ++nd)
        Pch[q * PSTR + nd * 16 + lcol] = f2bf(Oacc[mi][nd][r] * li);
    }
  __syncthreads();
#pragma unroll
  for (int i = 0; i < 4; ++i) {
    int c = tid + i * 256;
    int row = c >> 3, part = c & 7;
    uint4 v = *(const uint4*)((const unsigned short*)Pch + row * PSTR + part * 8);  // 176-B rows: aligned
    *(uint4*)(Ctx + ((size_t)(b * 2048 + qt * 128 + row)) * 1024 + h * 64 + part * 8) = v;
  }
}

// ---------------- launch ----------------
extern "C" void kernel_launch(void* const* d_in, const int* in_sizes, int n_in,
                              void* d_out, int out_size, void* d_ws, size_t ws_size,
                              hipStream_t stream) {
  // Documented contract: cast per reference dtypes -> fp32 inputs, fp32 output.
  const float* query = (const float*)d_in[0];
  const float* key_  = (const float*)d_in[1];
  const float* value = (const float*)d_in[2];
  const float* Wq = (const float*)d_in[3];
  const float* bq = (const float*)d_in[4];
  const float* Wk = (const float*)d_in[5];
  const float* bk = (const float*)d_in[6];
  const float* Wv = (const float*)d_in[7];
  const float* bv = (const float*)d_in[8];
  const float* Wo = (const float*)d_in[9];
  const float* bo = (const float*)d_in[10];

  char* w = (char*)d_ws;
  unsigned short* Wqb = (unsigned short*)w; w += (size_t)1024 * 1024 * 2;
  unsigned short* Wkb = (unsigned short*)w; w += (size_t)1024 * 1024 * 2;
  unsigned short* Wvb = (unsigned short*)w; w += (size_t)1024 * 1024 * 2;
  unsigned short* Wob = (unsigned short*)w; w += (size_t)1024 * 1024 * 2;
  unsigned short* Qp  = (unsigned short*)w; w += (size_t)8192 * 1024 * 2;
  unsigned short* Kp  = (unsigned short*)w; w += (size_t)8192 * 1024 * 2;
  unsigned short* Vp  = (unsigned short*)w; w += (size_t)8192 * 1024 * 2;
  unsigned short* Ctx = (unsigned short*)w; w += (size_t)8192 * 1024 * 2;

  cvt_kernel<<<1024, 256, 0, stream>>>(Wq, Wqb);
  cvt_kernel<<<1024, 256, 0, stream>>>(Wk, Wkb);
  cvt_kernel<<<1024, 256, 0, stream>>>(Wv, Wvb);
  cvt_kernel<<<1024, 256, 0, stream>>>(Wo, Wob);

  dim3 gg(8, 64);  // N/128, M/128
  gemm128<1><<<gg, 256, 0, stream>>>(query, Wqb, bq, Qp);
  gemm128<1><<<gg, 256, 0, stream>>>(key_,  Wkb, bk, Kp);
  gemm128<1><<<gg, 256, 0, stream>>>(value, Wvb, bv, Vp);

  attn_kernel<<<dim3(16, 16, 4), 256, 0, stream>>>(Qp, Kp, Vp, Ctx);

  gemm128<0><<<gg, 256, 0, stream>>>(Ctx, Wob, bo, (float*)d_out);
}

// Round 7
// 434.996 us; speedup vs baseline: 1.1108x; 1.1108x over previous
//
#include <hip/hip_runtime.h>
#include <stdint.h>

typedef __attribute__((ext_vector_type(8))) short short8;   // 8 x bf16 MFMA operand
typedef __attribute__((ext_vector_type(4))) float floatx4;  // MFMA accumulator

#define DEV __device__ __forceinline__

DEV unsigned short f2bf(float x) {  // fp32 -> bf16 RNE
  unsigned u = __float_as_uint(x);
  u += 0x7fffu + ((u >> 16) & 1u);
  return (unsigned short)(u >> 16);
}

DEV void load_lds16(const unsigned short* g, unsigned short* l) {
  __builtin_amdgcn_global_load_lds(
      (const __attribute__((address_space(1))) void*)g,
      (__attribute__((address_space(3))) void*)l, 16, 0, 0);
}

DEV void lds_fence() { asm volatile("" ::: "memory"); }  // wave-private LDS RAW/WAR: DS is in-order per wave; just stop compiler reordering

// ---------------- all 4 weights fp32 -> bf16, one dispatch ----------------
__global__ void cvt4_kernel(const float* __restrict__ a, const float* __restrict__ b,
                            const float* __restrict__ c, const float* __restrict__ d,
                            unsigned short* __restrict__ out) {
  int sel = blockIdx.x >> 10;
  const float* src = sel == 0 ? a : sel == 1 ? b : sel == 2 ? c : d;
  int off = ((blockIdx.x & 1023) * 256 + threadIdx.x) * 4;
  float4 v = *(const float4*)(src + off);
  ushort4 o;
  o.x = f2bf(v.x); o.y = f2bf(v.y); o.z = f2bf(v.z); o.w = f2bf(v.w);
  *(ushort4*)(out + (size_t)sel * 1048576 + off) = o;
}

// ---------------- fused QKV projection: one dispatch, grid (8,64,3) ----------------
// z=0: Qp[b,h,s,64] = query@Wq^T+bq   z=1: Kp[...] = key@Wk^T+bk
// z=2: VTp[b,h,64,s] = (value@Wv^T+bv)^T  -- computed as C[d][s] by swapping
//      which LDS tile feeds the MFMA A vs B operand.
__global__ __launch_bounds__(256, 2) void qkv_gemm(
    const float* __restrict__ Xq, const float* __restrict__ Xk, const float* __restrict__ Xv,
    const unsigned short* __restrict__ Wqb, const unsigned short* __restrict__ Wkb,
    const unsigned short* __restrict__ Wvb,
    const float* __restrict__ bq, const float* __restrict__ bk, const float* __restrict__ bv,
    unsigned short* __restrict__ Qp, unsigned short* __restrict__ Kp,
    unsigned short* __restrict__ VTp) {
  __shared__ alignas(16) unsigned short Xs[128 * 32];  // input rows (fp32->bf16 staged)
  __shared__ alignas(16) unsigned short Ws[128 * 32];  // weight rows (async bf16)
  const int z = blockIdx.z;
  const float* X = z == 0 ? Xq : z == 1 ? Xk : Xv;
  const unsigned short* Wb = z == 0 ? Wqb : z == 1 ? Wkb : Wvb;
  const float* bias = z == 0 ? bq : z == 1 ? bk : bv;

  const int tid = threadIdx.x;
  const int lane = tid & 63, wave = tid >> 6;
  const int lcol = lane & 15, quad = lane >> 4;
  const int wo = blockIdx.x * 128;  // d origin (weight rows)
  const int xo = blockIdx.y * 128;  // s origin (input rows)
  const int wm = (wave & 1) * 64;
  const int wn = (wave >> 1) * 64;

  floatx4 acc[4][4];
  for (int mi = 0; mi < 4; ++mi)
    for (int ni = 0; ni < 4; ++ni)
      for (int r = 0; r < 4; ++r) acc[mi][ni][r] = 0.f;

  const unsigned short* Abuf = (z < 2) ? Xs : Ws;  // MFMA A operand rows (m)
  const unsigned short* Bbuf = (z < 2) ? Ws : Xs;  // MFMA B operand rows (n)

  for (int kt = 0; kt < 32; ++kt) {
    const int k0 = kt * 32;
    {  // W tile 8192 B: async exact cover
      int c = tid;
      load_lds16(Wb + (size_t)(wo + (c >> 2)) * 1024 + k0 + (c & 3) * 8, Ws + c * 8);
      c = tid + 256;
      load_lds16(Wb + (size_t)(wo + (c >> 2)) * 1024 + k0 + (c & 3) * 8, Ws + c * 8);
    }
    {  // X tile: fp32 load + convert
#pragma unroll
      for (int i = 0; i < 4; ++i) {
        int f = tid + i * 256;
        int row = f >> 3, c4 = f & 7;
        float4 v = *(const float4*)(X + (size_t)(xo + row) * 1024 + k0 + c4 * 4);
        ushort4 o; o.x = f2bf(v.x); o.y = f2bf(v.y); o.z = f2bf(v.z); o.w = f2bf(v.w);
        *(ushort4*)(Xs + row * 32 + c4 * 4) = o;
      }
    }
    __syncthreads();
    short8 af[4], bf[4];
#pragma unroll
    for (int mi = 0; mi < 4; ++mi)
      af[mi] = *(const short8*)(Abuf + (wm + mi * 16 + lcol) * 32 + quad * 8);
#pragma unroll
    for (int ni = 0; ni < 4; ++ni)
      bf[ni] = *(const short8*)(Bbuf + (wn + ni * 16 + lcol) * 32 + quad * 8);
#pragma unroll
    for (int mi = 0; mi < 4; ++mi)
#pragma unroll
      for (int ni = 0; ni < 4; ++ni)
        acc[mi][ni] = __builtin_amdgcn_mfma_f32_16x16x32_bf16(af[mi], bf[ni], acc[mi][ni], 0, 0, 0);
    __syncthreads();
  }

  if (z < 2) {  // C[m=s][n=d] -> head-split [B,H,S,64]
    unsigned short* Out = z == 0 ? Qp : Kp;
#pragma unroll
    for (int ni = 0; ni < 4; ++ni) {
      int col = wo + wn + ni * 16 + lcol;
      float bvx = bias[col];
      int h = col >> 6, d = col & 63;
#pragma unroll
      for (int mi = 0; mi < 4; ++mi) {
        int rbase = xo + wm + mi * 16 + quad * 4;
#pragma unroll
        for (int r = 0; r < 4; ++r) {
          int grow = rbase + r;            // = b*2048 + s
          int bb = grow >> 11, s = grow & 2047;
          Out[((size_t)(bb * 16 + h) * 2048 + s) * 64 + d] = f2bf(acc[mi][ni][r] + bvx);
        }
      }
    }
  } else {  // C[m=d][n=s] -> V^T [B,H,64,S]
#pragma unroll
    for (int mi = 0; mi < 4; ++mi) {
      int dbase = wo + wm + mi * 16 + quad * 4;
#pragma unroll
      for (int r = 0; r < 4; ++r) {
        int dg = dbase + r;
        float bvx = bias[dg];
        int h = dg >> 6, dk = dg & 63;
#pragma unroll
        for (int ni = 0; ni < 4; ++ni) {
          int sg = xo + wn + ni * 16 + lcol;  // = b*2048 + s
          int bb = sg >> 11, ss = sg & 2047;
          VTp[((size_t)(bb * 16 + h) * 64 + dk) * 2048 + ss] = f2bf(acc[mi][ni][r] + bvx);
        }
      }
    }
  }
}

// ---------------- final O-projection: fp32 out ----------------
__global__ __launch_bounds__(256, 2) void gemm_o(
    const unsigned short* __restrict__ A, const unsigned short* __restrict__ Bw,
    const float* __restrict__ bias, float* __restrict__ Out) {
  __shared__ alignas(16) unsigned short As[128 * 32];
  __shared__ alignas(16) unsigned short Bs[128 * 32];
  const int tid = threadIdx.x;
  const int lane = tid & 63, wave = tid >> 6;
  const int lcol = lane & 15, quad = lane >> 4;
  const int n0 = blockIdx.x * 128;
  const int m0 = blockIdx.y * 128;
  const int wm = (wave & 1) * 64;
  const int wn = (wave >> 1) * 64;

  floatx4 acc[4][4];
  for (int mi = 0; mi < 4; ++mi)
    for (int ni = 0; ni < 4; ++ni)
      for (int r = 0; r < 4; ++r) acc[mi][ni][r] = 0.f;

  for (int kt = 0; kt < 32; ++kt) {
    const int k0 = kt * 32;
    int c = tid;
    load_lds16(Bw + (size_t)(n0 + (c >> 2)) * 1024 + k0 + (c & 3) * 8, Bs + c * 8);
    load_lds16(A  + (size_t)(m0 + (c >> 2)) * 1024 + k0 + (c & 3) * 8, As + c * 8);
    c = tid + 256;
    load_lds16(Bw + (size_t)(n0 + (c >> 2)) * 1024 + k0 + (c & 3) * 8, Bs + c * 8);
    load_lds16(A  + (size_t)(m0 + (c >> 2)) * 1024 + k0 + (c & 3) * 8, As + c * 8);
    __syncthreads();
    short8 af[4], bf[4];
#pragma unroll
    for (int mi = 0; mi < 4; ++mi)
      af[mi] = *(const short8*)(As + (wm + mi * 16 + lcol) * 32 + quad * 8);
#pragma unroll
    for (int ni = 0; ni < 4; ++ni)
      bf[ni] = *(const short8*)(Bs + (wn + ni * 16 + lcol) * 32 + quad * 8);
#pragma unroll
    for (int mi = 0; mi < 4; ++mi)
#pragma unroll
      for (int ni = 0; ni < 4; ++ni)
        acc[mi][ni] = __builtin_amdgcn_mfma_f32_16x16x32_bf16(af[mi], bf[ni], acc[mi][ni], 0, 0, 0);
    __syncthreads();
  }
#pragma unroll
  for (int ni = 0; ni < 4; ++ni) {
    int col = n0 + wn + ni * 16 + lcol;
    float bv = bias[col];
#pragma unroll
    for (int mi = 0; mi < 4; ++mi) {
      int rbase = m0 + wm + mi * 16 + quad * 4;
#pragma unroll
      for (int r = 0; r < 4; ++r)
        Out[(size_t)(rbase + r) * 1024 + col] = acc[mi][ni][r] + bv;
    }
  }
}

// ---------------- flash attention: one block = (b, h, 128 q rows) ----------------
// Round-7 restructure:
//  * V^T staged directly (produced by qkv_gemm z=2) -> no in-kernel transpose
//  * XOR-swizzled LDS chunk layouts (chunk ^= row&7): row strides 64/128 shorts
//    are 0 mod 32 dwords, so unswizzled b128 reads start at only 4 bank spans
//    (2x the 8-phase floor). Swizzle applied on the GLOBAL src address (LDS dest
//    of global_load_lds must stay lane-contiguous), reads use matching XOR.
//  * P half-tile aliases Ks (dead after QK) -> LDS 32.8 KB -> 4 blocks/CU
//  * wave-private P/O round-trips use compiler fences (DS in-order per wave);
//    3 block barriers/iter (was 7); alpha/linv via __shfl instead of LDS
__global__ __launch_bounds__(256, 2) void attn_kernel(
    const unsigned short* __restrict__ Qp, const unsigned short* __restrict__ Kp,
    const unsigned short* __restrict__ VTp, unsigned short* __restrict__ Ctx) {
  __shared__ alignas(16) unsigned short Ks[128 * 64];  // Q stage -> K tiles -> P half -> O stage
  __shared__ alignas(16) unsigned short Vt[64 * 128];  // V^T tile (swizzled chunks)

  const int tid = threadIdx.x;
  const int lane = tid & 63, wave = tid >> 6;
  const int lcol = lane & 15, quad = lane >> 4;
  const int wq = wave * 32;  // this wave's 32 q rows
  const int qt = blockIdx.x, h = blockIdx.y, b = blockIdx.z;
  const size_t bh = (size_t)(b * 16 + h) * 2048 * 64;
  const unsigned short* Qb = Qp + bh + (size_t)qt * 128 * 64;
  const unsigned short* Kb = Kp + bh;
  const unsigned short* VTb = VTp + (size_t)(b * 16 + h) * 64 * 2048;

  // prologue: Q tile into Ks, swizzled; fragments to registers
#pragma unroll
  for (int i = 0; i < 4; ++i) {
    int p = tid + i * 256;
    int row = p >> 3, pj = p & 7;
    load_lds16(Qb + row * 64 + ((pj ^ (row & 7)) * 8), Ks + p * 8);
  }
  __syncthreads();
  short8 qf[2][2];
#pragma unroll
  for (int ni = 0; ni < 2; ++ni)
#pragma unroll
    for (int ks = 0; ks < 2; ++ks) {
      int row = wq + ni * 16 + lcol;
      qf[ni][ks] = *(const short8*)(Ks + row * 64 + (((ks * 4 + quad) ^ (row & 7)) * 8));
    }

  float M[2] = {-1e30f, -1e30f};
  float L[2] = {0.f, 0.f};
  floatx4 Oacc[2][4];
  for (int mi = 0; mi < 2; ++mi)
    for (int nd = 0; nd < 4; ++nd)
      for (int r = 0; r < 4; ++r) Oacc[mi][nd][r] = 0.f;

  const float sc = 0.125f * 1.44269504089f;  // 1/sqrt(64) * log2(e)

  for (int jt = 0; jt < 16; ++jt) {
    __syncthreads();  // B0: prev-iter P/V reads done; Ks & Vt free; qf consumed
#pragma unroll
    for (int i = 0; i < 4; ++i) {
      int p = tid + i * 256;
      int kr = p >> 3, kj = p & 7;
      load_lds16(Kb + (size_t)jt * 8192 + kr * 64 + ((kj ^ (kr & 7)) * 8), Ks + p * 8);
      int vr = p >> 4, vj = p & 15;
      load_lds16(VTb + (size_t)vr * 2048 + jt * 128 + ((vj ^ (vr & 7)) * 8), Vt + p * 8);
    }
    __syncthreads();  // B1: tiles visible

    // S^T = K @ Q^T : m = kcol (8 tiles), n = q (2 tiles)
    floatx4 sacc[8][2];
    for (int mi = 0; mi < 8; ++mi)
      for (int ni = 0; ni < 2; ++ni)
        for (int r = 0; r < 4; ++r) sacc[mi][ni][r] = 0.f;
#pragma unroll
    for (int mi = 0; mi < 8; ++mi) {
      int row = mi * 16 + lcol;
      int sw = (row & 7);
      short8 kf0 = *(const short8*)(Ks + row * 64 + ((quad ^ sw) * 8));
      short8 kf1 = *(const short8*)(Ks + row * 64 + (((4 + quad) ^ sw) * 8));
#pragma unroll
      for (int ni = 0; ni < 2; ++ni) {
        sacc[mi][ni] = __builtin_amdgcn_mfma_f32_16x16x32_bf16(kf0, qf[ni][0], sacc[mi][ni], 0, 0, 0);
        sacc[mi][ni] = __builtin_amdgcn_mfma_f32_16x16x32_bf16(kf1, qf[ni][1], sacc[mi][ni], 0, 0, 0);
      }
    }

    // online softmax over kcol (per lane: fixed q = wq + ni*16 + lcol)
    float alpha[2];
#pragma unroll
    for (int ni = 0; ni < 2; ++ni) {
      float mx = -1e30f;
#pragma unroll
      for (int mi = 0; mi < 8; ++mi)
#pragma unroll
        for (int r = 0; r < 4; ++r) mx = fmaxf(mx, sacc[mi][ni][r]);
      mx = fmaxf(mx, __shfl_xor(mx, 16));
      mx = fmaxf(mx, __shfl_xor(mx, 32));
      float mnew = fmaxf(M[ni], mx * sc);
      alpha[ni] = exp2f(M[ni] - mnew);
      M[ni] = mnew;
      float rs = 0.f;
#pragma unroll
      for (int mi = 0; mi < 8; ++mi)
#pragma unroll
        for (int r = 0; r < 4; ++r) {
          float p = exp2f(sacc[mi][ni][r] * sc - mnew);
          sacc[mi][ni][r] = p;
          rs += p;
        }
      rs += __shfl_xor(rs, 16);
      rs += __shfl_xor(rs, 32);
      L[ni] = L[ni] * alpha[ni] + rs;
    }
    // rescale O: alpha for C-layout row (quad*4+r) fetched by shuffle
    // (alpha[ni] is quad-uniform after the xor16/xor32 reductions)
#pragma unroll
    for (int mi = 0; mi < 2; ++mi)
#pragma unroll
      for (int r = 0; r < 4; ++r) {
        float a = __shfl(alpha[mi], quad * 4 + r);
#pragma unroll
        for (int nd = 0; nd < 4; ++nd) Oacc[mi][nd][r] *= a;
      }

    __syncthreads();  // B2: all waves done reading Ks (K-frags) before P overwrites it

    // P (bf16, 2 halves of 64 kcols) -> Ks alias; wave-private rows, fence-ordered
#pragma unroll
    for (int half = 0; half < 2; ++half) {
#pragma unroll
      for (int ni = 0; ni < 2; ++ni) {
        int q = wq + ni * 16 + lcol;
        int sw = q & 7;
#pragma unroll
        for (int m2 = 0; m2 < 4; ++m2) {
          int mi = half * 4 + m2;
          ushort4 pk;
          pk.x = f2bf(sacc[mi][ni][0]);
          pk.y = f2bf(sacc[mi][ni][1]);
          pk.z = f2bf(sacc[mi][ni][2]);
          pk.w = f2bf(sacc[mi][ni][3]);
          int j = 2 * m2 + (quad >> 1);
          *(ushort4*)(Ks + q * 64 + ((j ^ sw) * 8) + (quad & 1) * 4) = pk;
        }
      }
      lds_fence();
#pragma unroll
      for (int kk = 0; kk < 2; ++kk) {
        short8 pf[2];
#pragma unroll
        for (int mi = 0; mi < 2; ++mi) {
          int q = wq + mi * 16 + lcol;
          pf[mi] = *(const short8*)(Ks + q * 64 + (((4 * kk + quad) ^ (q & 7)) * 8));
        }
#pragma unroll
        for (int nd = 0; nd < 4; ++nd) {
          int d = nd * 16 + lcol;
          short8 vf = *(const short8*)(Vt + d * 128 + ((((half * 2 + kk) * 4 + quad) ^ (d & 7)) * 8));
#pragma unroll
          for (int mi = 0; mi < 2; ++mi)
            Oacc[mi][nd] = __builtin_amdgcn_mfma_f32_16x16x32_bf16(pf[mi], vf, Oacc[mi][nd], 0, 0, 0);
        }
      }
      lds_fence();  // half-1 rewrite / next-iter restage ordered after reads (wave-private)
    }
  }

  // epilogue: O/L -> bf16 into Ks (wave-private rows, swizzled), then coalesced store
  float linv[2] = {1.f / L[0], 1.f / L[1]};
#pragma unroll
  for (int mi = 0; mi < 2; ++mi)
#pragma unroll
    for (int r = 0; r < 4; ++r) {
      float li = __shfl(linv[mi], quad * 4 + r);
      int q = wq + mi * 16 + quad * 4 + r;
      int sw = q & 7;
#pragma unroll
      for (int nd = 0; nd < 4; ++nd) {
        int j = 2 * nd + (lcol >> 3);
        Ks[q * 64 + ((j ^ sw) * 8) + (lcol & 7)] = f2bf(Oacc[mi][nd][r] * li);
      }
    }
  __syncthreads();
#pragma unroll
  for (int i = 0; i < 4; ++i) {
    int c = tid + i * 256;
    int row = c >> 3, pj = c & 7;
    uint4 v = *(const uint4*)(Ks + row * 64 + ((pj ^ (row & 7)) * 8));
    *(uint4*)(Ctx + ((size_t)(b * 2048 + qt * 128 + row)) * 1024 + h * 64 + pj * 8) = v;
  }
}

// ---------------- launch ----------------
extern "C" void kernel_launch(void* const* d_in, const int* in_sizes, int n_in,
                              void* d_out, int out_size, void* d_ws, size_t ws_size,
                              hipStream_t stream) {
  const float* query = (const float*)d_in[0];
  const float* key_  = (const float*)d_in[1];
  const float* value = (const float*)d_in[2];
  const float* Wq = (const float*)d_in[3];
  const float* bq = (const float*)d_in[4];
  const float* Wk = (const float*)d_in[5];
  const float* bk = (const float*)d_in[6];
  const float* Wv = (const float*)d_in[7];
  const float* bv = (const float*)d_in[8];
  const float* Wo = (const float*)d_in[9];
  const float* bo = (const float*)d_in[10];

  char* w = (char*)d_ws;
  unsigned short* Wqb = (unsigned short*)w; w += (size_t)1024 * 1024 * 2;  // cvt4 writes the 4
  unsigned short* Wkb = (unsigned short*)w; w += (size_t)1024 * 1024 * 2;  // weight blobs
  unsigned short* Wvb = (unsigned short*)w; w += (size_t)1024 * 1024 * 2;  // contiguously
  unsigned short* Wob = (unsigned short*)w; w += (size_t)1024 * 1024 * 2;
  unsigned short* Qp  = (unsigned short*)w; w += (size_t)8192 * 1024 * 2;  // [B,H,S,64]
  unsigned short* Kp  = (unsigned short*)w; w += (size_t)8192 * 1024 * 2;  // [B,H,S,64]
  unsigned short* VTp = (unsigned short*)w; w += (size_t)8192 * 1024 * 2;  // [B,H,64,S]
  unsigned short* Ctx = (unsigned short*)w; w += (size_t)8192 * 1024 * 2;  // [B,S,1024]

  cvt4_kernel<<<4096, 256, 0, stream>>>(Wq, Wk, Wv, Wo, Wqb);

  qkv_gemm<<<dim3(8, 64, 3), 256, 0, stream>>>(query, key_, value, Wqb, Wkb, Wvb,
                                               bq, bk, bv, Qp, Kp, VTp);

  attn_kernel<<<dim3(16, 16, 4), 256, 0, stream>>>(Qp, Kp, VTp, Ctx);

  gemm_o<<<dim3(8, 64), 256, 0, stream>>>(Ctx, Wob, bo, (float*)d_out);
}

// Round 8
// 416.681 us; speedup vs baseline: 1.1596x; 1.0440x over previous
//
#include <hip/hip_runtime.h>
#include <stdint.h>

typedef __attribute__((ext_vector_type(8))) short short8;   // 8 x bf16 MFMA operand
typedef __attribute__((ext_vector_type(4))) float floatx4;  // MFMA accumulator

#define DEV __device__ __forceinline__

DEV unsigned short f2bf(float x) {  // fp32 -> bf16 RNE (epilogue-only; hot paths use pkbf)
  unsigned u = __float_as_uint(x);
  u += 0x7fffu + ((u >> 16) & 1u);
  return (unsigned short)(u >> 16);
}

// pack two fp32 -> two bf16 (round-half-up) in 3 VALU: 2 adds + v_perm
// dst low16 = bf16(lo), high16 = bf16(hi)
DEV unsigned pkbf(float hi, float lo) {
  return __builtin_amdgcn_perm(__float_as_uint(hi) + 0x8000u,
                               __float_as_uint(lo) + 0x8000u, 0x07060302u);
}

DEV void load_lds16(const unsigned short* g, unsigned short* l) {
  __builtin_amdgcn_global_load_lds(
      (const __attribute__((address_space(1))) void*)g,
      (__attribute__((address_space(3))) void*)l, 16, 0, 0);
}

DEV void lds_fence() { asm volatile("" ::: "memory"); }  // wave-private LDS RAW/WAR ordering

// ---------------- one-shot fp32 -> bf16 of all 7 tensors ----------------
// blocks 0..4095: weights (4 x 1M floats, contiguous out). 4096..28671: activations.
__global__ void cvt_all(const float* __restrict__ Wq, const float* __restrict__ Wk,
                        const float* __restrict__ Wv, const float* __restrict__ Wo,
                        const float* __restrict__ Xq, const float* __restrict__ Xk,
                        const float* __restrict__ Xv,
                        unsigned short* __restrict__ Wb, unsigned short* __restrict__ XqB,
                        unsigned short* __restrict__ XkB, unsigned short* __restrict__ XvB) {
  int bid = blockIdx.x;
  const float* src;
  unsigned short* dst;
  int off;
  if (bid < 4096) {
    int sel = bid >> 10;
    src = sel == 0 ? Wq : sel == 1 ? Wk : sel == 2 ? Wv : Wo;
    dst = Wb + (size_t)sel * 1048576;
    off = bid & 1023;
  } else {
    bid -= 4096;
    int sel = bid >> 13;
    src = sel == 0 ? Xq : sel == 1 ? Xk : Xv;
    dst = sel == 0 ? XqB : sel == 1 ? XkB : XvB;
    off = bid & 8191;
  }
  int i = (off * 256 + threadIdx.x) * 4;
  float4 v = *(const float4*)(src + i);
  uint2 o;
  o.x = pkbf(v.y, v.x);
  o.y = pkbf(v.w, v.z);
  *(uint2*)(dst + i) = o;
}

// ---------------- fused QKV projection: all-bf16 async staging, grid (8,64,3) ----------------
// z=0: Qp[b,h,s,64] = (q@Wq^T+bq) * SCQ  (softmax scale folded in, base-2 units)
// z=1: Kp[b,h,s,64] = k@Wk^T+bk
// z=2: VTp[b,h,64,s] = (v@Wv^T+bv)^T  (A/B operand roles swapped)
#define SCQ (0.125f * 1.44269504089f)
__global__ __launch_bounds__(256, 2) void qkv_gemm(
    const unsigned short* __restrict__ XqB, const unsigned short* __restrict__ XkB,
    const unsigned short* __restrict__ XvB,
    const unsigned short* __restrict__ Wb,
    const float* __restrict__ bq, const float* __restrict__ bk, const float* __restrict__ bv,
    unsigned short* __restrict__ Qp, unsigned short* __restrict__ Kp,
    unsigned short* __restrict__ VTp) {
  __shared__ alignas(16) unsigned short Xs[128 * 32];
  __shared__ alignas(16) unsigned short Ws[128 * 32];
  const int z = blockIdx.z;
  const unsigned short* X = z == 0 ? XqB : z == 1 ? XkB : XvB;
  const unsigned short* W = Wb + (size_t)z * 1048576;
  const float* bias = z == 0 ? bq : z == 1 ? bk : bv;

  const int tid = threadIdx.x;
  const int lane = tid & 63, wave = tid >> 6;
  const int lcol = lane & 15, quad = lane >> 4;
  const int wo = blockIdx.x * 128;  // d origin (weight rows)
  const int xo = blockIdx.y * 128;  // s origin (input rows)
  const int wm = (wave & 1) * 64;
  const int wn = (wave >> 1) * 64;

  floatx4 acc[4][4];
  for (int mi = 0; mi < 4; ++mi)
    for (int ni = 0; ni < 4; ++ni)
      for (int r = 0; r < 4; ++r) acc[mi][ni][r] = 0.f;

  const unsigned short* Abuf = (z < 2) ? Xs : Ws;  // MFMA A operand rows (m)
  const unsigned short* Bbuf = (z < 2) ? Ws : Xs;  // MFMA B operand rows (n)

  for (int kt = 0; kt < 32; ++kt) {
    const int k0 = kt * 32;
    int c = tid;
    load_lds16(W + (size_t)(wo + (c >> 2)) * 1024 + k0 + (c & 3) * 8, Ws + c * 8);
    load_lds16(X + (size_t)(xo + (c >> 2)) * 1024 + k0 + (c & 3) * 8, Xs + c * 8);
    c = tid + 256;
    load_lds16(W + (size_t)(wo + (c >> 2)) * 1024 + k0 + (c & 3) * 8, Ws + c * 8);
    load_lds16(X + (size_t)(xo + (c >> 2)) * 1024 + k0 + (c & 3) * 8, Xs + c * 8);
    __syncthreads();
    short8 af[4], bf[4];
#pragma unroll
    for (int mi = 0; mi < 4; ++mi)
      af[mi] = *(const short8*)(Abuf + (wm + mi * 16 + lcol) * 32 + quad * 8);
#pragma unroll
    for (int ni = 0; ni < 4; ++ni)
      bf[ni] = *(const short8*)(Bbuf + (wn + ni * 16 + lcol) * 32 + quad * 8);
#pragma unroll
    for (int mi = 0; mi < 4; ++mi)
#pragma unroll
      for (int ni = 0; ni < 4; ++ni)
        acc[mi][ni] = __builtin_amdgcn_mfma_f32_16x16x32_bf16(af[mi], bf[ni], acc[mi][ni], 0, 0, 0);
    __syncthreads();
  }

  if (z < 2) {  // C[m=s][n=d] -> head-split [B,H,S,64]
    unsigned short* Out = z == 0 ? Qp : Kp;
    const float scl = z == 0 ? SCQ : 1.f;
#pragma unroll
    for (int ni = 0; ni < 4; ++ni) {
      int col = wo + wn + ni * 16 + lcol;
      float bvx = bias[col];
      int h = col >> 6, d = col & 63;
#pragma unroll
      for (int mi = 0; mi < 4; ++mi) {
        int rbase = xo + wm + mi * 16 + quad * 4;
#pragma unroll
        for (int r = 0; r < 4; ++r) {
          int grow = rbase + r;            // = b*2048 + s
          int bb = grow >> 11, s = grow & 2047;
          Out[((size_t)(bb * 16 + h) * 2048 + s) * 64 + d] = f2bf((acc[mi][ni][r] + bvx) * scl);
        }
      }
    }
  } else {  // C[m=d][n=s] -> V^T [B,H,64,S]
#pragma unroll
    for (int mi = 0; mi < 4; ++mi) {
      int dbase = wo + wm + mi * 16 + quad * 4;
#pragma unroll
      for (int r = 0; r < 4; ++r) {
        int dg = dbase + r;
        float bvx = bias[dg];
        int h = dg >> 6, dk = dg & 63;
#pragma unroll
        for (int ni = 0; ni < 4; ++ni) {
          int sg = xo + wn + ni * 16 + lcol;  // = b*2048 + s
          int bb = sg >> 11, ss = sg & 2047;
          VTp[((size_t)(bb * 16 + h) * 64 + dk) * 2048 + ss] = f2bf(acc[mi][ni][r] + bvx);
        }
      }
    }
  }
}

// ---------------- final O-projection: fp32 out ----------------
__global__ __launch_bounds__(256, 2) void gemm_o(
    const unsigned short* __restrict__ A, const unsigned short* __restrict__ Bw,
    const float* __restrict__ bias, float* __restrict__ Out) {
  __shared__ alignas(16) unsigned short As[128 * 32];
  __shared__ alignas(16) unsigned short Bs[128 * 32];
  const int tid = threadIdx.x;
  const int lane = tid & 63, wave = tid >> 6;
  const int lcol = lane & 15, quad = lane >> 4;
  const int n0 = blockIdx.x * 128;
  const int m0 = blockIdx.y * 128;
  const int wm = (wave & 1) * 64;
  const int wn = (wave >> 1) * 64;

  floatx4 acc[4][4];
  for (int mi = 0; mi < 4; ++mi)
    for (int ni = 0; ni < 4; ++ni)
      for (int r = 0; r < 4; ++r) acc[mi][ni][r] = 0.f;

  for (int kt = 0; kt < 32; ++kt) {
    const int k0 = kt * 32;
    int c = tid;
    load_lds16(Bw + (size_t)(n0 + (c >> 2)) * 1024 + k0 + (c & 3) * 8, Bs + c * 8);
    load_lds16(A  + (size_t)(m0 + (c >> 2)) * 1024 + k0 + (c & 3) * 8, As + c * 8);
    c = tid + 256;
    load_lds16(Bw + (size_t)(n0 + (c >> 2)) * 1024 + k0 + (c & 3) * 8, Bs + c * 8);
    load_lds16(A  + (size_t)(m0 + (c >> 2)) * 1024 + k0 + (c & 3) * 8, As + c * 8);
    __syncthreads();
    short8 af[4], bf[4];
#pragma unroll
    for (int mi = 0; mi < 4; ++mi)
      af[mi] = *(const short8*)(As + (wm + mi * 16 + lcol) * 32 + quad * 8);
#pragma unroll
    for (int ni = 0; ni < 4; ++ni)
      bf[ni] = *(const short8*)(Bs + (wn + ni * 16 + lcol) * 32 + quad * 8);
#pragma unroll
    for (int mi = 0; mi < 4; ++mi)
#pragma unroll
      for (int ni = 0; ni < 4; ++ni)
        acc[mi][ni] = __builtin_amdgcn_mfma_f32_16x16x32_bf16(af[mi], bf[ni], acc[mi][ni], 0, 0, 0);
    __syncthreads();
  }
#pragma unroll
  for (int ni = 0; ni < 4; ++ni) {
    int col = n0 + wn + ni * 16 + lcol;
    float bv = bias[col];
#pragma unroll
    for (int mi = 0; mi < 4; ++mi) {
      int rbase = m0 + wm + mi * 16 + quad * 4;
#pragma unroll
      for (int r = 0; r < 4; ++r)
        Out[(size_t)(rbase + r) * 1024 + col] = acc[mi][ni][r] + bv;
    }
  }
}

// ---------------- flash attention: one block = (b, h, 128 q rows) ----------------
// r7 structure (V^T input, XOR-swizzled LDS, P aliases Ks, 3 barriers/iter) plus:
//  * Q pre-scaled by SCQ at projection -> softmax is sub+exp2 (no muls)
//  * P pack via v_perm (3 VALU / 2 values instead of 6)
__global__ __launch_bounds__(256, 2) void attn_kernel(
    const unsigned short* __restrict__ Qp, const unsigned short* __restrict__ Kp,
    const unsigned short* __restrict__ VTp, unsigned short* __restrict__ Ctx) {
  __shared__ alignas(16) unsigned short Ks[128 * 64];  // Q stage -> K tiles -> P half -> O stage
  __shared__ alignas(16) unsigned short Vt[64 * 128];  // V^T tile (swizzled chunks)

  const int tid = threadIdx.x;
  const int lane = tid & 63, wave = tid >> 6;
  const int lcol = lane & 15, quad = lane >> 4;
  const int wq = wave * 32;
  const int qt = blockIdx.x, h = blockIdx.y, b = blockIdx.z;
  const size_t bh = (size_t)(b * 16 + h) * 2048 * 64;
  const unsigned short* Qb = Qp + bh + (size_t)qt * 128 * 64;
  const unsigned short* Kb = Kp + bh;
  const unsigned short* VTb = VTp + (size_t)(b * 16 + h) * 64 * 2048;

  // prologue: Q tile into Ks, swizzled; fragments to registers
#pragma unroll
  for (int i = 0; i < 4; ++i) {
    int p = tid + i * 256;
    int row = p >> 3, pj = p & 7;
    load_lds16(Qb + row * 64 + ((pj ^ (row & 7)) * 8), Ks + p * 8);
  }
  __syncthreads();
  short8 qf[2][2];
#pragma unroll
  for (int ni = 0; ni < 2; ++ni)
#pragma unroll
    for (int ks = 0; ks < 2; ++ks) {
      int row = wq + ni * 16 + lcol;
      qf[ni][ks] = *(const short8*)(Ks + row * 64 + (((ks * 4 + quad) ^ (row & 7)) * 8));
    }

  float M[2] = {-1e30f, -1e30f};
  float L[2] = {0.f, 0.f};
  floatx4 Oacc[2][4];
  for (int mi = 0; mi < 2; ++mi)
    for (int nd = 0; nd < 4; ++nd)
      for (int r = 0; r < 4; ++r) Oacc[mi][nd][r] = 0.f;

  for (int jt = 0; jt < 16; ++jt) {
    __syncthreads();  // B0: prev-iter P/V reads done; Ks & Vt free
#pragma unroll
    for (int i = 0; i < 4; ++i) {
      int p = tid + i * 256;
      int kr = p >> 3, kj = p & 7;
      load_lds16(Kb + (size_t)jt * 8192 + kr * 64 + ((kj ^ (kr & 7)) * 8), Ks + p * 8);
      int vr = p >> 4, vj = p & 15;
      load_lds16(VTb + (size_t)vr * 2048 + jt * 128 + ((vj ^ (vr & 7)) * 8), Vt + p * 8);
    }
    __syncthreads();  // B1: tiles visible

    // S^T = K @ Q^T  (Q pre-scaled: sacc already in base-2 logit units)
    floatx4 sacc[8][2];
    for (int mi = 0; mi < 8; ++mi)
      for (int ni = 0; ni < 2; ++ni)
        for (int r = 0; r < 4; ++r) sacc[mi][ni][r] = 0.f;
#pragma unroll
    for (int mi = 0; mi < 8; ++mi) {
      int row = mi * 16 + lcol;
      int sw = (row & 7);
      short8 kf0 = *(const short8*)(Ks + row * 64 + ((quad ^ sw) * 8));
      short8 kf1 = *(const short8*)(Ks + row * 64 + (((4 + quad) ^ sw) * 8));
#pragma unroll
      for (int ni = 0; ni < 2; ++ni) {
        sacc[mi][ni] = __builtin_amdgcn_mfma_f32_16x16x32_bf16(kf0, qf[ni][0], sacc[mi][ni], 0, 0, 0);
        sacc[mi][ni] = __builtin_amdgcn_mfma_f32_16x16x32_bf16(kf1, qf[ni][1], sacc[mi][ni], 0, 0, 0);
      }
    }

    // online softmax over kcol
    float alpha[2];
#pragma unroll
    for (int ni = 0; ni < 2; ++ni) {
      float mx = -1e30f;
#pragma unroll
      for (int mi = 0; mi < 8; ++mi)
#pragma unroll
        for (int r = 0; r < 4; ++r) mx = fmaxf(mx, sacc[mi][ni][r]);
      mx = fmaxf(mx, __shfl_xor(mx, 16));
      mx = fmaxf(mx, __shfl_xor(mx, 32));
      float mnew = fmaxf(M[ni], mx);
      alpha[ni] = exp2f(M[ni] - mnew);
      M[ni] = mnew;
      float rs = 0.f;
#pragma unroll
      for (int mi = 0; mi < 8; ++mi)
#pragma unroll
        for (int r = 0; r < 4; ++r) {
          float p = exp2f(sacc[mi][ni][r] - mnew);
          sacc[mi][ni][r] = p;
          rs += p;
        }
      rs += __shfl_xor(rs, 16);
      rs += __shfl_xor(rs, 32);
      L[ni] = L[ni] * alpha[ni] + rs;
    }
    // rescale O (alpha is quad-uniform; fetch C-layout row's alpha by shuffle)
#pragma unroll
    for (int mi = 0; mi < 2; ++mi)
#pragma unroll
      for (int r = 0; r < 4; ++r) {
        float a = __shfl(alpha[mi], quad * 4 + r);
#pragma unroll
        for (int nd = 0; nd < 4; ++nd) Oacc[mi][nd][r] *= a;
      }

    __syncthreads();  // B2: all waves done reading Ks before P overwrites it

    // P (2 halves of 64 kcols) -> Ks alias; perm-packed writes; fence-ordered
#pragma unroll
    for (int half = 0; half < 2; ++half) {
#pragma unroll
      for (int ni = 0; ni < 2; ++ni) {
        int q = wq + ni * 16 + lcol;
        int sw = q & 7;
#pragma unroll
        for (int m2 = 0; m2 < 4; ++m2) {
          int mi = half * 4 + m2;
          uint2 pw;
          pw.x = pkbf(sacc[mi][ni][1], sacc[mi][ni][0]);
          pw.y = pkbf(sacc[mi][ni][3], sacc[mi][ni][2]);
          int j = 2 * m2 + (quad >> 1);
          *(uint2*)(Ks + q * 64 + ((j ^ sw) * 8) + (quad & 1) * 4) = pw;
        }
      }
      lds_fence();
#pragma unroll
      for (int kk = 0; kk < 2; ++kk) {
        short8 pf[2];
#pragma unroll
        for (int mi = 0; mi < 2; ++mi) {
          int q = wq + mi * 16 + lcol;
          pf[mi] = *(const short8*)(Ks + q * 64 + (((4 * kk + quad) ^ (q & 7)) * 8));
        }
#pragma unroll
        for (int nd = 0; nd < 4; ++nd) {
          int d = nd * 16 + lcol;
          short8 vf = *(const short8*)(Vt + d * 128 + ((((half * 2 + kk) * 4 + quad) ^ (d & 7)) * 8));
#pragma unroll
          for (int mi = 0; mi < 2; ++mi)
            Oacc[mi][nd] = __builtin_amdgcn_mfma_f32_16x16x32_bf16(pf[mi], vf, Oacc[mi][nd], 0, 0, 0);
        }
      }
      lds_fence();
    }
  }

  // epilogue: O/L -> bf16 into Ks (swizzled), then coalesced store
  float linv[2] = {1.f / L[0], 1.f / L[1]};
#pragma unroll
  for (int mi = 0; mi < 2; ++mi)
#pragma unroll
    for (int r = 0; r < 4; ++r) {
      float li = __shfl(linv[mi], quad * 4 + r);
      int q = wq + mi * 16 + quad * 4 + r;
      int sw = q & 7;
#pragma unroll
      for (int nd = 0; nd < 4; ++nd) {
        int j = 2 * nd + (lcol >> 3);
        Ks[q * 64 + ((j ^ sw) * 8) + (lcol & 7)] = f2bf(Oacc[mi][nd][r] * li);
      }
    }
  __syncthreads();
#pragma unroll
  for (int i = 0; i < 4; ++i) {
    int c = tid + i * 256;
    int row = c >> 3, pj = c & 7;
    uint4 v = *(const uint4*)(Ks + row * 64 + ((pj ^ (row & 7)) * 8));
    *(uint4*)(Ctx + ((size_t)(b * 2048 + qt * 128 + row)) * 1024 + h * 64 + pj * 8) = v;
  }
}

// ---------------- launch ----------------
extern "C" void kernel_launch(void* const* d_in, const int* in_sizes, int n_in,
                              void* d_out, int out_size, void* d_ws, size_t ws_size,
                              hipStream_t stream) {
  const float* query = (const float*)d_in[0];
  const float* key_  = (const float*)d_in[1];
  const float* value = (const float*)d_in[2];
  const float* Wq = (const float*)d_in[3];
  const float* bq = (const float*)d_in[4];
  const float* Wk = (const float*)d_in[5];
  const float* bk = (const float*)d_in[6];
  const float* Wv = (const float*)d_in[7];
  const float* bv = (const float*)d_in[8];
  const float* Wo = (const float*)d_in[9];
  const float* bo = (const float*)d_in[10];

  char* w = (char*)d_ws;
  unsigned short* Wb  = (unsigned short*)w; w += (size_t)4 * 1024 * 1024 * 2;  // Wq,Wk,Wv,Wo bf16
  unsigned short* Qp  = (unsigned short*)w; w += (size_t)8192 * 1024 * 2;      // [B,H,S,64]
  unsigned short* Kp  = (unsigned short*)w; w += (size_t)8192 * 1024 * 2;      // [B,H,S,64]
  unsigned short* VTp = (unsigned short*)w; w += (size_t)8192 * 1024 * 2;      // [B,H,64,S]
  unsigned short* Ctx = (unsigned short*)w; w += (size_t)8192 * 1024 * 2;      // [B,S,1024]

  // bf16 activations: query/key park in d_out (32 MB, dead until gemm_o);
  // value parks in the Ctx slot (dead once qkv_gemm completes, before attn writes Ctx).
  unsigned short* XqB = (unsigned short*)d_out;
  unsigned short* XkB = (unsigned short*)d_out + (size_t)8192 * 1024;
  unsigned short* XvB = Ctx;

  cvt_all<<<28672, 256, 0, stream>>>(Wq, Wk, Wv, Wo, query, key_, value,
                                     Wb, XqB, XkB, XvB);

  qkv_gemm<<<dim3(8, 64, 3), 256, 0, stream>>>(XqB, XkB, XvB, Wb,
                                               bq, bk, bv, Qp, Kp, VTp);

  attn_kernel<<<dim3(16, 16, 4), 256, 0, stream>>>(Qp, Kp, VTp, Ctx);

  gemm_o<<<dim3(8, 64), 256, 0, stream>>>(Ctx, Wb + (size_t)3 * 1048576, bo, (float*)d_out);
}